// Round 7
// baseline (107.845 us; speedup 1.0000x reference)
//
#include <hip/hip_runtime.h>
#include <math.h>

typedef float f32x4 __attribute__((ext_vector_type(4)));

// bf16 decode helpers: value stored in low/high 16 bits of a u32 word.
__device__ __forceinline__ float bf_lo(unsigned w) {
    return __uint_as_float(w << 16);
}
__device__ __forceinline__ float bf_hi(unsigned w) {
    return __uint_as_float(w & 0xffff0000u);
}
__device__ __forceinline__ unsigned bf16_rne(float f) {
    unsigned u = __float_as_uint(f);
    return (u + 0x7fffu + ((u >> 16) & 1u)) >> 16;   // round-to-nearest-even
}

// Compiler-only memory fence: forbids IR/MIR reordering of the LDS phases.
// HW needs nothing extra: a wave's DS ops execute in order in the LDS pipe.
#define WAVE_FENCE() asm volatile("" ::: "memory")

// ---------------------------------------------------------------------------
// Kernel 1: per-camera precompute into a 32-byte record (L1-resident table):
//   u32[0..3] = R0..R7 as bf16 pairs (row-major), u32[4] = R8 (lo half),
//   u32[5..7] = t0,t1,t2 as f32.  1000 cams * 32 B = 32 KB.
// ---------------------------------------------------------------------------
__global__ void cam_precompute(const float* __restrict__ params,
                               unsigned* __restrict__ cams, int size) {
    int c = blockIdx.x * blockDim.x + threadIdx.x;
    if (c >= size) return;
    float a  = params[6 * c + 0];
    float b  = params[6 * c + 1];
    float cc = params[6 * c + 2];
    float t2 = a * a + b * b + cc * cc;
    float t  = sqrtf(t2);
    float sin_c, cos_c;
    if (t < 1e-8f) {
        sin_c = 1.0f;
        cos_c = 0.5f;
    } else {
        sin_c = sinf(t) / t;
        cos_c = (1.0f - cosf(t)) / t2;
    }
    float sa = sin_c * a, sb = sin_c * b, sc = sin_c * cc;
    float cab = cos_c * a * b, cac = cos_c * a * cc, cbc = cos_c * b * cc;

    float r0 = 1.0f - cos_c * (a * a + b * b);
    float r1 =  sa - cbc;
    float r2 =  sb + cac;
    float r3 = -sa - cbc;
    float r4 = 1.0f - cos_c * (a * a + cc * cc);
    float r5 =  sc - cab;
    float r6 = -sb + cac;
    float r7 = -sc - cab;
    float r8 = 1.0f - cos_c * (b * b + cc * cc);

    unsigned* o = cams + 8 * c;
    o[0] = bf16_rne(r0) | (bf16_rne(r1) << 16);
    o[1] = bf16_rne(r2) | (bf16_rne(r3) << 16);
    o[2] = bf16_rne(r4) | (bf16_rne(r5) << 16);
    o[3] = bf16_rne(r6) | (bf16_rne(r7) << 16);
    o[4] = bf16_rne(r8);
    o[5] = __float_as_uint(params[6 * c + 3]);
    o[6] = __float_as_uint(params[6 * c + 4]);
    o[7] = __float_as_uint(params[6 * c + 5]);
}

// ---------------------------------------------------------------------------
// Kernel 2: BARRIER-FREE wave-autonomous version. Each wave owns 256
// consecutive points (lane l owns points l+64k, k=0..3) and uses a PRIVATE
// 6 KB LDS region as its transpose arena, so all exchanges are intra-wave:
// no __syncthreads anywhere in the hot path. All global traffic is dense
// per-instruction f32x4. LDS scalar access at word-stride 3 / 9 (coprime
// 32 banks -> at most 2-way alias = free).
// out layout (floats): [new_o: 3N][new_d: 3N][trans: 3N][R: 9N]
// ---------------------------------------------------------------------------
__launch_bounds__(256, 4)
__global__ void cam_apply(const int* __restrict__ idx,
                          const float* __restrict__ of,
                          const float* __restrict__ df,
                          const uint4* __restrict__ cams8,
                          float* __restrict__ out,
                          long long N) {
    __shared__ float lds[6144];                 // 24 KB = 4 waves * 6 KB
    const int tid = threadIdx.x;
    const int wid = tid >> 6;
    const int l   = tid & 63;
    float* buf = &lds[wid * 1536];              // bufA = [0,768), bufB = [768,1536)
    f32x4* bA4 = (f32x4*)buf;
    f32x4* bB4 = (f32x4*)(buf + 768);

    const long long base = ((long long)blockIdx.x * 4 + wid) * 256;

    if (base + 256 <= N) {
        // ---- prologue: issue all global loads (dense) ----
        int id[4];
#pragma unroll
        for (int k = 0; k < 4; ++k) id[k] = idx[base + l + 64 * k];

        const f32x4* o4 = (const f32x4*)(of + 3 * base);   // 192 slots
        const f32x4* d4 = (const f32x4*)(df + 3 * base);
        f32x4 ov[3], dv[3];
#pragma unroll
        for (int j = 0; j < 3; ++j) { ov[j] = o4[l + 64 * j];
                                      dv[j] = d4[l + 64 * j]; }

        uint4 q0[4], q1[4];
#pragma unroll
        for (int k = 0; k < 4; ++k) {
            const uint4* cp = cams8 + 2 * (long long)id[k];
            q0[k] = cp[0]; q1[k] = cp[1];
        }

        // ---- stage o,d into wave-private arena ----
#pragma unroll
        for (int j = 0; j < 3; ++j) { bA4[l + 64 * j] = ov[j];
                                      bB4[l + 64 * j] = dv[j]; }
        WAVE_FENCE();

        // ---- per-point gather-decode + compute ----
        float R[4][9], T[4][3], no[4][3], nd[4][3];
#pragma unroll
        for (int k = 0; k < 4; ++k) {
            int p = l + 64 * k;
            float ox = buf[3 * p + 0], oy = buf[3 * p + 1], oz = buf[3 * p + 2];
            float dx = buf[768 + 3 * p + 0], dy = buf[768 + 3 * p + 1],
                  dz = buf[768 + 3 * p + 2];

            R[k][0] = bf_lo(q0[k].x); R[k][1] = bf_hi(q0[k].x);
            R[k][2] = bf_lo(q0[k].y); R[k][3] = bf_hi(q0[k].y);
            R[k][4] = bf_lo(q0[k].z); R[k][5] = bf_hi(q0[k].z);
            R[k][6] = bf_lo(q0[k].w); R[k][7] = bf_hi(q0[k].w);
            R[k][8] = bf_lo(q1[k].x);
            T[k][0] = __uint_as_float(q1[k].y);
            T[k][1] = __uint_as_float(q1[k].z);
            T[k][2] = __uint_as_float(q1[k].w);

            no[k][0] = R[k][0] * ox + R[k][1] * oy + R[k][2] * oz + T[k][0];
            no[k][1] = R[k][3] * ox + R[k][4] * oy + R[k][5] * oz + T[k][1];
            no[k][2] = R[k][6] * ox + R[k][7] * oy + R[k][8] * oz + T[k][2];

            nd[k][0] = R[k][0] * dx + R[k][1] * dy + R[k][2] * dz;
            nd[k][1] = R[k][3] * dx + R[k][4] * dy + R[k][5] * dz;
            nd[k][2] = R[k][6] * dx + R[k][7] * dy + R[k][8] * dz;
        }
        WAVE_FENCE();

        // ---- exchange + flush new_o (bufA), new_d (bufB) ----
#pragma unroll
        for (int k = 0; k < 4; ++k) {
            int p = l + 64 * k;
            buf[3 * p + 0] = no[k][0];
            buf[3 * p + 1] = no[k][1];
            buf[3 * p + 2] = no[k][2];
            buf[768 + 3 * p + 0] = nd[k][0];
            buf[768 + 3 * p + 1] = nd[k][1];
            buf[768 + 3 * p + 2] = nd[k][2];
        }
        WAVE_FENCE();
        f32x4* g0 = (f32x4*)(out + 3 * base);
        f32x4* g1 = (f32x4*)(out + 3 * N + 3 * base);
#pragma unroll
        for (int j = 0; j < 3; ++j) { g0[l + 64 * j] = bA4[l + 64 * j];
                                      g1[l + 64 * j] = bB4[l + 64 * j]; }
        WAVE_FENCE();

        // ---- exchange + flush trans (bufA) ----
#pragma unroll
        for (int k = 0; k < 4; ++k) {
            int p = l + 64 * k;
            buf[3 * p + 0] = T[k][0];
            buf[3 * p + 1] = T[k][1];
            buf[3 * p + 2] = T[k][2];
        }
        WAVE_FENCE();
        f32x4* g2 = (f32x4*)(out + 6 * N + 3 * base);
#pragma unroll
        for (int j = 0; j < 3; ++j) g2[l + 64 * j] = bA4[l + 64 * j];
        WAVE_FENCE();

        // ---- R: 4 chunks of 64 points; lane's chunk-k point is its k-th cam ----
        f32x4* g3 = (f32x4*)(out + 9 * N + 9 * base);
#pragma unroll
        for (int k = 0; k < 4; ++k) {
#pragma unroll
            for (int e = 0; e < 9; ++e) buf[9 * l + e] = R[k][e];
            WAVE_FENCE();
            // 64 pts * 9 floats = 144 f32x4 slots, dense flush
#pragma unroll
            for (int j = 0; j < 3; ++j) {
                int s = l + 64 * j;
                if (s < 144) g3[144 * k + s] = bA4[s];
            }
            WAVE_FENCE();
        }
    } else if (base < N) {
        // ---- tail: scalar guarded path ----
        for (int k = 0; k < 4; ++k) {
            long long n = base + l + 64 * k;
            if (n >= N) continue;
            int cid = idx[n];
            const uint4* cp = cams8 + 2 * (long long)cid;
            uint4 q0 = cp[0], q1 = cp[1];
            float Rv[9] = {bf_lo(q0.x), bf_hi(q0.x), bf_lo(q0.y), bf_hi(q0.y),
                           bf_lo(q0.z), bf_hi(q0.z), bf_lo(q0.w), bf_hi(q0.w),
                           bf_lo(q1.x)};
            float t0 = __uint_as_float(q1.y), t1 = __uint_as_float(q1.z),
                  t2 = __uint_as_float(q1.w);
            float ox = of[3 * n + 0], oy = of[3 * n + 1], oz = of[3 * n + 2];
            float dx = df[3 * n + 0], dy = df[3 * n + 1], dz = df[3 * n + 2];

            out[3 * n + 0] = Rv[0] * ox + Rv[1] * oy + Rv[2] * oz + t0;
            out[3 * n + 1] = Rv[3] * ox + Rv[4] * oy + Rv[5] * oz + t1;
            out[3 * n + 2] = Rv[6] * ox + Rv[7] * oy + Rv[8] * oz + t2;

            out[3 * N + 3 * n + 0] = Rv[0] * dx + Rv[1] * dy + Rv[2] * dz;
            out[3 * N + 3 * n + 1] = Rv[3] * dx + Rv[4] * dy + Rv[5] * dz;
            out[3 * N + 3 * n + 2] = Rv[6] * dx + Rv[7] * dy + Rv[8] * dz;

            out[6 * N + 3 * n + 0] = t0;
            out[6 * N + 3 * n + 1] = t1;
            out[6 * N + 3 * n + 2] = t2;

            for (int j = 0; j < 9; ++j) out[9 * N + 9 * n + j] = Rv[j];
        }
    }
}

extern "C" void kernel_launch(void* const* d_in, const int* in_sizes, int n_in,
                              void* d_out, int out_size, void* d_ws, size_t ws_size,
                              hipStream_t stream) {
    const float* params = (const float*)d_in[0];
    const int*   idx    = (const int*)d_in[1];
    const float* o      = (const float*)d_in[2];
    const float* d      = (const float*)d_in[3];
    float*       out    = (float*)d_out;
    unsigned*    cams   = (unsigned*)d_ws;   // size*8 u32 (32 KB for size=1000)

    int size = in_sizes[0] / 6;
    long long N = (long long)in_sizes[2] / 3;

    cam_precompute<<<(size + 255) / 256, 256, 0, stream>>>(params, cams, size);

    int blocks = (int)((N + 1023) / 1024);
    cam_apply<<<blocks, 256, 0, stream>>>(idx, o, d, (const uint4*)cams,
                                          out, N);
}

// Round 8
// 88.962 us; speedup vs baseline: 1.2123x; 1.2123x over previous
//
#include <hip/hip_runtime.h>
#include <math.h>

typedef float f32x4 __attribute__((ext_vector_type(4)));

// bf16 decode helpers: value stored in low/high 16 bits of a u32 word.
__device__ __forceinline__ float bf_lo(unsigned w) {
    return __uint_as_float(w << 16);
}
__device__ __forceinline__ float bf_hi(unsigned w) {
    return __uint_as_float(w & 0xffff0000u);
}
__device__ __forceinline__ unsigned bf16_rne(float f) {
    unsigned u = __float_as_uint(f);
    return (u + 0x7fffu + ((u >> 16) & 1u)) >> 16;   // round-to-nearest-even
}

// ---------------------------------------------------------------------------
// Kernel 1: per-camera precompute into a 32-byte record (L1-resident table):
//   u32[0..3] = R0..R7 as bf16 pairs (row-major), u32[4] = R8 (lo half),
//   u32[5..7] = t0,t1,t2 as f32.  1000 cams * 32 B = 32 KB.
// ---------------------------------------------------------------------------
__global__ void cam_precompute(const float* __restrict__ params,
                               unsigned* __restrict__ cams, int size) {
    int c = blockIdx.x * blockDim.x + threadIdx.x;
    if (c >= size) return;
    float a  = params[6 * c + 0];
    float b  = params[6 * c + 1];
    float cc = params[6 * c + 2];
    float t2 = a * a + b * b + cc * cc;
    float t  = sqrtf(t2);
    float sin_c, cos_c;
    if (t < 1e-8f) {
        sin_c = 1.0f;
        cos_c = 0.5f;
    } else {
        sin_c = sinf(t) / t;
        cos_c = (1.0f - cosf(t)) / t2;
    }
    float sa = sin_c * a, sb = sin_c * b, sc = sin_c * cc;
    float cab = cos_c * a * b, cac = cos_c * a * cc, cbc = cos_c * b * cc;

    float r0 = 1.0f - cos_c * (a * a + b * b);
    float r1 =  sa - cbc;
    float r2 =  sb + cac;
    float r3 = -sa - cbc;
    float r4 = 1.0f - cos_c * (a * a + cc * cc);
    float r5 =  sc - cab;
    float r6 = -sb + cac;
    float r7 = -sc - cab;
    float r8 = 1.0f - cos_c * (b * b + cc * cc);

    unsigned* o = cams + 8 * c;
    o[0] = bf16_rne(r0) | (bf16_rne(r1) << 16);
    o[1] = bf16_rne(r2) | (bf16_rne(r3) << 16);
    o[2] = bf16_rne(r4) | (bf16_rne(r5) << 16);
    o[3] = bf16_rne(r6) | (bf16_rne(r7) << 16);
    o[4] = bf16_rne(r8);
    o[5] = __float_as_uint(params[6 * c + 3]);
    o[6] = __float_as_uint(params[6 * c + 4]);
    o[7] = __float_as_uint(params[6 * c + 5]);
}

// ---------------------------------------------------------------------------
// Kernel 2: 1024-pt tile, 256 threads; thread owns 4 CONSECUTIVE points
// (4*tid+e). All LDS traffic is ds_read_b128/ds_write_b128 at lane word
// strides 12 / 36 -- gcd(12,32)=4 with 4-word groups => every 8 lanes cover
// all 32 banks exactly once (conflict-free). In-place no/nd overwrite of the
// o/d slots removes one barrier (4 total). idx = one dense int4 per thread.
// out layout (floats): [new_o: 3N][new_d: 3N][trans: 3N][R: 9N]
// ---------------------------------------------------------------------------
__launch_bounds__(256, 4)
__global__ void cam_apply(const int* __restrict__ idx,
                          const float* __restrict__ of,
                          const float* __restrict__ df,
                          const uint4* __restrict__ cams8,
                          float* __restrict__ out,
                          long long N) {
    __shared__ f32x4 arena[2304];   // 9216 floats = 36 KB -> 4 blocks/CU
    const int tid = threadIdx.x;
    const long long tileBase = (long long)blockIdx.x * 1024;

    if (tileBase + 1024 <= N) {
        // ---- P1: dense stage of o,d; idx as one int4 ----
        const f32x4* o4 = (const f32x4*)(of + 3 * tileBase);   // 768 slots
        const f32x4* d4 = (const f32x4*)(df + 3 * tileBase);
#pragma unroll
        for (int j = 0; j < 3; ++j) arena[tid + 256 * j]       = o4[tid + 256 * j];
#pragma unroll
        for (int j = 0; j < 3; ++j) arena[768 + tid + 256 * j] = d4[tid + 256 * j];
        int4 I = ((const int4*)idx)[(tileBase >> 2) + tid];
        __syncthreads();

        // ---- P2: camera gathers (L1-resident) + own-slot b128 reads ----
        int id[4] = {I.x, I.y, I.z, I.w};
        uint4 q0[4], q1[4];
#pragma unroll
        for (int e = 0; e < 4; ++e) {
            const uint4* cp = cams8 + 2 * (long long)id[e];
            q0[e] = cp[0]; q1[e] = cp[1];
        }
        f32x4 ov0 = arena[3 * tid + 0], ov1 = arena[3 * tid + 1],
              ov2 = arena[3 * tid + 2];
        f32x4 dv0 = arena[768 + 3 * tid + 0], dv1 = arena[768 + 3 * tid + 1],
              dv2 = arena[768 + 3 * tid + 2];

        float ox[4] = {ov0[0], ov0[3], ov1[2], ov2[1]};
        float oy[4] = {ov0[1], ov1[0], ov1[3], ov2[2]};
        float oz[4] = {ov0[2], ov1[1], ov2[0], ov2[3]};
        float dx[4] = {dv0[0], dv0[3], dv1[2], dv2[1]};
        float dy[4] = {dv0[1], dv1[0], dv1[3], dv2[2]};
        float dz[4] = {dv0[2], dv1[1], dv2[0], dv2[3]};

        float R[4][9], T[4][3], no[12], nd[12];
#pragma unroll
        for (int e = 0; e < 4; ++e) {
            R[e][0] = bf_lo(q0[e].x); R[e][1] = bf_hi(q0[e].x);
            R[e][2] = bf_lo(q0[e].y); R[e][3] = bf_hi(q0[e].y);
            R[e][4] = bf_lo(q0[e].z); R[e][5] = bf_hi(q0[e].z);
            R[e][6] = bf_lo(q0[e].w); R[e][7] = bf_hi(q0[e].w);
            R[e][8] = bf_lo(q1[e].x);
            T[e][0] = __uint_as_float(q1[e].y);
            T[e][1] = __uint_as_float(q1[e].z);
            T[e][2] = __uint_as_float(q1[e].w);

            no[3 * e + 0] = R[e][0] * ox[e] + R[e][1] * oy[e] + R[e][2] * oz[e] + T[e][0];
            no[3 * e + 1] = R[e][3] * ox[e] + R[e][4] * oy[e] + R[e][5] * oz[e] + T[e][1];
            no[3 * e + 2] = R[e][6] * ox[e] + R[e][7] * oy[e] + R[e][8] * oz[e] + T[e][2];

            nd[3 * e + 0] = R[e][0] * dx[e] + R[e][1] * dy[e] + R[e][2] * dz[e];
            nd[3 * e + 1] = R[e][3] * dx[e] + R[e][4] * dy[e] + R[e][5] * dz[e];
            nd[3 * e + 2] = R[e][6] * dx[e] + R[e][7] * dy[e] + R[e][8] * dz[e];
        }

        // ---- P3: in-place b128 write-back (same thread's own words) ----
        arena[3 * tid + 0] = (f32x4){no[0], no[1], no[2],  no[3]};
        arena[3 * tid + 1] = (f32x4){no[4], no[5], no[6],  no[7]};
        arena[3 * tid + 2] = (f32x4){no[8], no[9], no[10], no[11]};
        arena[768 + 3 * tid + 0] = (f32x4){nd[0], nd[1], nd[2],  nd[3]};
        arena[768 + 3 * tid + 1] = (f32x4){nd[4], nd[5], nd[6],  nd[7]};
        arena[768 + 3 * tid + 2] = (f32x4){nd[8], nd[9], nd[10], nd[11]};
        arena[1536 + 3 * tid + 0] = (f32x4){T[0][0], T[0][1], T[0][2], T[1][0]};
        arena[1536 + 3 * tid + 1] = (f32x4){T[1][1], T[1][2], T[2][0], T[2][1]};
        arena[1536 + 3 * tid + 2] = (f32x4){T[2][2], T[3][0], T[3][1], T[3][2]};
        __syncthreads();

        // ---- P4: dense flush of new_o, new_d, trans ----
        f32x4* g0 = (f32x4*)(out + 3 * tileBase);
        f32x4* g1 = (f32x4*)(out + 3 * N + 3 * tileBase);
        f32x4* g2 = (f32x4*)(out + 6 * N + 3 * tileBase);
#pragma unroll
        for (int j = 0; j < 3; ++j) g0[tid + 256 * j] = arena[tid + 256 * j];
#pragma unroll
        for (int j = 0; j < 3; ++j) g1[tid + 256 * j] = arena[768 + tid + 256 * j];
#pragma unroll
        for (int j = 0; j < 3; ++j) g2[tid + 256 * j] = arena[1536 + tid + 256 * j];
        __syncthreads();

        // ---- P5: R exchange, 9 b128 per thread at slot 9*tid ----
        float Rf[36];
#pragma unroll
        for (int e = 0; e < 4; ++e)
#pragma unroll
            for (int m = 0; m < 9; ++m) Rf[9 * e + m] = R[e][m];
#pragma unroll
        for (int j = 0; j < 9; ++j)
            arena[9 * tid + j] = (f32x4){Rf[4 * j + 0], Rf[4 * j + 1],
                                         Rf[4 * j + 2], Rf[4 * j + 3]};
        __syncthreads();

        // ---- P6: dense flush of R (2304 slots) ----
        f32x4* g3 = (f32x4*)(out + 9 * N + 9 * tileBase);
#pragma unroll
        for (int j = 0; j < 9; ++j) g3[tid + 256 * j] = arena[tid + 256 * j];
    } else {
        // ---- tail: scalar guarded path ----
        for (int e = 0; e < 4; ++e) {
            long long n = tileBase + 4LL * tid + e;
            if (n >= N) continue;
            int cid = idx[n];
            const uint4* cp = cams8 + 2 * (long long)cid;
            uint4 q0 = cp[0], q1 = cp[1];
            float Rv[9] = {bf_lo(q0.x), bf_hi(q0.x), bf_lo(q0.y), bf_hi(q0.y),
                           bf_lo(q0.z), bf_hi(q0.z), bf_lo(q0.w), bf_hi(q0.w),
                           bf_lo(q1.x)};
            float t0 = __uint_as_float(q1.y), t1 = __uint_as_float(q1.z),
                  t2 = __uint_as_float(q1.w);
            float ox = of[3 * n + 0], oy = of[3 * n + 1], oz = of[3 * n + 2];
            float dx = df[3 * n + 0], dy = df[3 * n + 1], dz = df[3 * n + 2];

            out[3 * n + 0] = Rv[0] * ox + Rv[1] * oy + Rv[2] * oz + t0;
            out[3 * n + 1] = Rv[3] * ox + Rv[4] * oy + Rv[5] * oz + t1;
            out[3 * n + 2] = Rv[6] * ox + Rv[7] * oy + Rv[8] * oz + t2;

            out[3 * N + 3 * n + 0] = Rv[0] * dx + Rv[1] * dy + Rv[2] * dz;
            out[3 * N + 3 * n + 1] = Rv[3] * dx + Rv[4] * dy + Rv[5] * dz;
            out[3 * N + 3 * n + 2] = Rv[6] * dx + Rv[7] * dy + Rv[8] * dz;

            out[6 * N + 3 * n + 0] = t0;
            out[6 * N + 3 * n + 1] = t1;
            out[6 * N + 3 * n + 2] = t2;

            for (int j = 0; j < 9; ++j) out[9 * N + 9 * n + j] = Rv[j];
        }
    }
}

extern "C" void kernel_launch(void* const* d_in, const int* in_sizes, int n_in,
                              void* d_out, int out_size, void* d_ws, size_t ws_size,
                              hipStream_t stream) {
    const float* params = (const float*)d_in[0];
    const int*   idx    = (const int*)d_in[1];
    const float* o      = (const float*)d_in[2];
    const float* d      = (const float*)d_in[3];
    float*       out    = (float*)d_out;
    unsigned*    cams   = (unsigned*)d_ws;   // size*8 u32 (32 KB for size=1000)

    int size = in_sizes[0] / 6;
    long long N = (long long)in_sizes[2] / 3;

    cam_precompute<<<(size + 255) / 256, 256, 0, stream>>>(params, cams, size);

    int blocks = (int)((N + 1023) / 1024);
    cam_apply<<<blocks, 256, 0, stream>>>(idx, o, d, (const uint4*)cams,
                                          out, N);
}

// Round 9
// 71.386 us; speedup vs baseline: 1.5107x; 1.2462x over previous
//
#include <hip/hip_runtime.h>
#include <math.h>

typedef float f32x4 __attribute__((ext_vector_type(4)));

// bf16 decode helpers: value stored in low/high 16 bits of a u32 word.
__device__ __forceinline__ float bf_lo(unsigned w) {
    return __uint_as_float(w << 16);
}
__device__ __forceinline__ float bf_hi(unsigned w) {
    return __uint_as_float(w & 0xffff0000u);
}
__device__ __forceinline__ unsigned bf16_rne(float f) {
    unsigned u = __float_as_uint(f);
    return (u + 0x7fffu + ((u >> 16) & 1u)) >> 16;   // round-to-nearest-even
}

// ---------------------------------------------------------------------------
// Kernel 1: per-camera precompute into a 32-byte record (L1-resident table):
//   u32[0..3] = R0..R7 as bf16 pairs (row-major), u32[4] = R8 (lo half),
//   u32[5..7] = t0,t1,t2 as f32.  1000 cams * 32 B = 32 KB.
// ---------------------------------------------------------------------------
__global__ void cam_precompute(const float* __restrict__ params,
                               unsigned* __restrict__ cams, int size) {
    int c = blockIdx.x * blockDim.x + threadIdx.x;
    if (c >= size) return;
    float a  = params[6 * c + 0];
    float b  = params[6 * c + 1];
    float cc = params[6 * c + 2];
    float t2 = a * a + b * b + cc * cc;
    float t  = sqrtf(t2);
    float sin_c, cos_c;
    if (t < 1e-8f) {
        sin_c = 1.0f;
        cos_c = 0.5f;
    } else {
        sin_c = sinf(t) / t;
        cos_c = (1.0f - cosf(t)) / t2;
    }
    float sa = sin_c * a, sb = sin_c * b, sc = sin_c * cc;
    float cab = cos_c * a * b, cac = cos_c * a * cc, cbc = cos_c * b * cc;

    float r0 = 1.0f - cos_c * (a * a + b * b);
    float r1 =  sa - cbc;
    float r2 =  sb + cac;
    float r3 = -sa - cbc;
    float r4 = 1.0f - cos_c * (a * a + cc * cc);
    float r5 =  sc - cab;
    float r6 = -sb + cac;
    float r7 = -sc - cab;
    float r8 = 1.0f - cos_c * (b * b + cc * cc);

    unsigned* o = cams + 8 * c;
    o[0] = bf16_rne(r0) | (bf16_rne(r1) << 16);
    o[1] = bf16_rne(r2) | (bf16_rne(r3) << 16);
    o[2] = bf16_rne(r4) | (bf16_rne(r5) << 16);
    o[3] = bf16_rne(r6) | (bf16_rne(r7) << 16);
    o[4] = bf16_rne(r8);
    o[5] = __float_as_uint(params[6 * c + 3]);
    o[6] = __float_as_uint(params[6 * c + 4]);
    o[7] = __float_as_uint(params[6 * c + 5]);
}

// ---------------------------------------------------------------------------
// Kernel 2: identical to the 89.0us R8 kernel (1024-pt tile, 4 consecutive
// points/thread, b128-only LDS, in-place overwrite) with ONE delta: the 18
// dense flush stores are NONTEMPORAL (full-line, so no sector amplification;
// evict-first keeps the 112 MB input set L3-resident across graph replays).
// out layout (floats): [new_o: 3N][new_d: 3N][trans: 3N][R: 9N]
// ---------------------------------------------------------------------------
__launch_bounds__(256, 4)
__global__ void cam_apply(const int* __restrict__ idx,
                          const float* __restrict__ of,
                          const float* __restrict__ df,
                          const uint4* __restrict__ cams8,
                          float* __restrict__ out,
                          long long N) {
    __shared__ f32x4 arena[2304];   // 9216 floats = 36 KB -> 4 blocks/CU
    const int tid = threadIdx.x;
    const long long tileBase = (long long)blockIdx.x * 1024;

    if (tileBase + 1024 <= N) {
        // ---- P1: dense stage of o,d; idx as one int4 ----
        const f32x4* o4 = (const f32x4*)(of + 3 * tileBase);   // 768 slots
        const f32x4* d4 = (const f32x4*)(df + 3 * tileBase);
#pragma unroll
        for (int j = 0; j < 3; ++j) arena[tid + 256 * j]       = o4[tid + 256 * j];
#pragma unroll
        for (int j = 0; j < 3; ++j) arena[768 + tid + 256 * j] = d4[tid + 256 * j];
        int4 I = ((const int4*)idx)[(tileBase >> 2) + tid];
        __syncthreads();

        // ---- P2: camera gathers (L1-resident) + own-slot b128 reads ----
        int id[4] = {I.x, I.y, I.z, I.w};
        uint4 q0[4], q1[4];
#pragma unroll
        for (int e = 0; e < 4; ++e) {
            const uint4* cp = cams8 + 2 * (long long)id[e];
            q0[e] = cp[0]; q1[e] = cp[1];
        }
        f32x4 ov0 = arena[3 * tid + 0], ov1 = arena[3 * tid + 1],
              ov2 = arena[3 * tid + 2];
        f32x4 dv0 = arena[768 + 3 * tid + 0], dv1 = arena[768 + 3 * tid + 1],
              dv2 = arena[768 + 3 * tid + 2];

        float ox[4] = {ov0[0], ov0[3], ov1[2], ov2[1]};
        float oy[4] = {ov0[1], ov1[0], ov1[3], ov2[2]};
        float oz[4] = {ov0[2], ov1[1], ov2[0], ov2[3]};
        float dx[4] = {dv0[0], dv0[3], dv1[2], dv2[1]};
        float dy[4] = {dv0[1], dv1[0], dv1[3], dv2[2]};
        float dz[4] = {dv0[2], dv1[1], dv2[0], dv2[3]};

        float R[4][9], T[4][3], no[12], nd[12];
#pragma unroll
        for (int e = 0; e < 4; ++e) {
            R[e][0] = bf_lo(q0[e].x); R[e][1] = bf_hi(q0[e].x);
            R[e][2] = bf_lo(q0[e].y); R[e][3] = bf_hi(q0[e].y);
            R[e][4] = bf_lo(q0[e].z); R[e][5] = bf_hi(q0[e].z);
            R[e][6] = bf_lo(q0[e].w); R[e][7] = bf_hi(q0[e].w);
            R[e][8] = bf_lo(q1[e].x);
            T[e][0] = __uint_as_float(q1[e].y);
            T[e][1] = __uint_as_float(q1[e].z);
            T[e][2] = __uint_as_float(q1[e].w);

            no[3 * e + 0] = R[e][0] * ox[e] + R[e][1] * oy[e] + R[e][2] * oz[e] + T[e][0];
            no[3 * e + 1] = R[e][3] * ox[e] + R[e][4] * oy[e] + R[e][5] * oz[e] + T[e][1];
            no[3 * e + 2] = R[e][6] * ox[e] + R[e][7] * oy[e] + R[e][8] * oz[e] + T[e][2];

            nd[3 * e + 0] = R[e][0] * dx[e] + R[e][1] * dy[e] + R[e][2] * dz[e];
            nd[3 * e + 1] = R[e][3] * dx[e] + R[e][4] * dy[e] + R[e][5] * dz[e];
            nd[3 * e + 2] = R[e][6] * dx[e] + R[e][7] * dy[e] + R[e][8] * dz[e];
        }

        // ---- P3: in-place b128 write-back (same thread's own words) ----
        arena[3 * tid + 0] = (f32x4){no[0], no[1], no[2],  no[3]};
        arena[3 * tid + 1] = (f32x4){no[4], no[5], no[6],  no[7]};
        arena[3 * tid + 2] = (f32x4){no[8], no[9], no[10], no[11]};
        arena[768 + 3 * tid + 0] = (f32x4){nd[0], nd[1], nd[2],  nd[3]};
        arena[768 + 3 * tid + 1] = (f32x4){nd[4], nd[5], nd[6],  nd[7]};
        arena[768 + 3 * tid + 2] = (f32x4){nd[8], nd[9], nd[10], nd[11]};
        arena[1536 + 3 * tid + 0] = (f32x4){T[0][0], T[0][1], T[0][2], T[1][0]};
        arena[1536 + 3 * tid + 1] = (f32x4){T[1][1], T[1][2], T[2][0], T[2][1]};
        arena[1536 + 3 * tid + 2] = (f32x4){T[2][2], T[3][0], T[3][1], T[3][2]};
        __syncthreads();

        // ---- P4: dense NONTEMPORAL flush of new_o, new_d, trans ----
        f32x4* g0 = (f32x4*)(out + 3 * tileBase);
        f32x4* g1 = (f32x4*)(out + 3 * N + 3 * tileBase);
        f32x4* g2 = (f32x4*)(out + 6 * N + 3 * tileBase);
#pragma unroll
        for (int j = 0; j < 3; ++j)
            __builtin_nontemporal_store(arena[tid + 256 * j], &g0[tid + 256 * j]);
#pragma unroll
        for (int j = 0; j < 3; ++j)
            __builtin_nontemporal_store(arena[768 + tid + 256 * j], &g1[tid + 256 * j]);
#pragma unroll
        for (int j = 0; j < 3; ++j)
            __builtin_nontemporal_store(arena[1536 + tid + 256 * j], &g2[tid + 256 * j]);
        __syncthreads();

        // ---- P5: R exchange, 9 b128 per thread at slot 9*tid ----
        float Rf[36];
#pragma unroll
        for (int e = 0; e < 4; ++e)
#pragma unroll
            for (int m = 0; m < 9; ++m) Rf[9 * e + m] = R[e][m];
#pragma unroll
        for (int j = 0; j < 9; ++j)
            arena[9 * tid + j] = (f32x4){Rf[4 * j + 0], Rf[4 * j + 1],
                                         Rf[4 * j + 2], Rf[4 * j + 3]};
        __syncthreads();

        // ---- P6: dense NONTEMPORAL flush of R (2304 slots) ----
        f32x4* g3 = (f32x4*)(out + 9 * N + 9 * tileBase);
#pragma unroll
        for (int j = 0; j < 9; ++j)
            __builtin_nontemporal_store(arena[tid + 256 * j], &g3[tid + 256 * j]);
    } else {
        // ---- tail: scalar guarded path ----
        for (int e = 0; e < 4; ++e) {
            long long n = tileBase + 4LL * tid + e;
            if (n >= N) continue;
            int cid = idx[n];
            const uint4* cp = cams8 + 2 * (long long)cid;
            uint4 q0 = cp[0], q1 = cp[1];
            float Rv[9] = {bf_lo(q0.x), bf_hi(q0.x), bf_lo(q0.y), bf_hi(q0.y),
                           bf_lo(q0.z), bf_hi(q0.z), bf_lo(q0.w), bf_hi(q0.w),
                           bf_lo(q1.x)};
            float t0 = __uint_as_float(q1.y), t1 = __uint_as_float(q1.z),
                  t2 = __uint_as_float(q1.w);
            float ox = of[3 * n + 0], oy = of[3 * n + 1], oz = of[3 * n + 2];
            float dx = df[3 * n + 0], dy = df[3 * n + 1], dz = df[3 * n + 2];

            out[3 * n + 0] = Rv[0] * ox + Rv[1] * oy + Rv[2] * oz + t0;
            out[3 * n + 1] = Rv[3] * ox + Rv[4] * oy + Rv[5] * oz + t1;
            out[3 * n + 2] = Rv[6] * ox + Rv[7] * oy + Rv[8] * oz + t2;

            out[3 * N + 3 * n + 0] = Rv[0] * dx + Rv[1] * dy + Rv[2] * dz;
            out[3 * N + 3 * n + 1] = Rv[3] * dx + Rv[4] * dy + Rv[5] * dz;
            out[3 * N + 3 * n + 2] = Rv[6] * dx + Rv[7] * dy + Rv[8] * dz;

            out[6 * N + 3 * n + 0] = t0;
            out[6 * N + 3 * n + 1] = t1;
            out[6 * N + 3 * n + 2] = t2;

            for (int j = 0; j < 9; ++j) out[9 * N + 9 * n + j] = Rv[j];
        }
    }
}

extern "C" void kernel_launch(void* const* d_in, const int* in_sizes, int n_in,
                              void* d_out, int out_size, void* d_ws, size_t ws_size,
                              hipStream_t stream) {
    const float* params = (const float*)d_in[0];
    const int*   idx    = (const int*)d_in[1];
    const float* o      = (const float*)d_in[2];
    const float* d      = (const float*)d_in[3];
    float*       out    = (float*)d_out;
    unsigned*    cams   = (unsigned*)d_ws;   // size*8 u32 (32 KB for size=1000)

    int size = in_sizes[0] / 6;
    long long N = (long long)in_sizes[2] / 3;

    cam_precompute<<<(size + 255) / 256, 256, 0, stream>>>(params, cams, size);

    int blocks = (int)((N + 1023) / 1024);
    cam_apply<<<blocks, 256, 0, stream>>>(idx, o, d, (const uint4*)cams,
                                          out, N);
}